// Round 1
// 459.390 us; speedup vs baseline: 1.5306x; 1.5306x over previous
//
#include <hip/hip_runtime.h>
#include <math.h>

// Problem constants (fixed by setup_inputs)
#define N_TOK 16384   // B*S
#define D_DIM 2048
#define H_DIM 256
#define E_NUM 5
#define R_DIM 16
#define ER 80         // E*R

#define NCT 21        // 16 W1 col-tiles + 5 A' col-tiles (16 cols each)
#define KG_N 64       // 2048 / 32 K-steps

typedef _Float16 half8 __attribute__((ext_vector_type(8)));
typedef float f32x4 __attribute__((ext_vector_type(4)));

// ---------------------------------------------------------------------------
// pack_w: W1[2048][256] and A'[2048][80] (A'[d][e*16+r] = A[e][d][r]) -> f16
// hi/lo fragment-linear arrays. For col-tile ct (0..20), K-step kg (0..63),
// lane l (0..63), j (0..7):
//   Wp[((ct*64+kg)*64+l)*8+j] = W[kg*32 + (l>>4)*8 + j][ct*16 + (l&15)]
// so the main kernel's B-fragment load is one coalesced dwordx4 per lane.
// hi = f16(v), lo = f16(v - hi)  (split-f16: 3-product emulation ~ fp32).
// ---------------------------------------------------------------------------
__global__ __launch_bounds__(256) void pack_w_kernel(
    const float* __restrict__ W1, const float* __restrict__ A,
    _Float16* __restrict__ Whi, _Float16* __restrict__ Wlo) {
  const int idx = blockIdx.x * 256 + threadIdx.x;  // 21*64*64 = 86016 exact
  const int lane = idx & 63;
  const int kgct = idx >> 6;              // ct*64 + kg, 0..1343
  const int kg = kgct & 63;
  const int ct = kgct >> 6;               // 0..20
  const int k0 = kg * 32 + ((lane >> 4) << 3);
  const int par = lane & 15;
  float v[8];
  if (ct < 16) {
    const int col = ct * 16 + par;
#pragma unroll
    for (int j = 0; j < 8; ++j) v[j] = W1[(size_t)(k0 + j) * H_DIM + col];
  } else {
    const float* Ae = A + (size_t)(ct - 16) * D_DIM * R_DIM;
#pragma unroll
    for (int j = 0; j < 8; ++j) v[j] = Ae[(size_t)(k0 + j) * R_DIM + par];
  }
  half8 hv, lv;
#pragma unroll
  for (int j = 0; j < 8; ++j) {
    const _Float16 hh = (_Float16)v[j];
    hv[j] = hh;
    lv[j] = (_Float16)(v[j] - (float)hh);
  }
  ((half8*)Whi)[(size_t)kgct * 64 + lane] = hv;
  ((half8*)Wlo)[(size_t)kgct * 64 + lane] = lv;
}

// ---------------------------------------------------------------------------
// xgemm: grid (N_TOK/64, 3). MFMA 16x16x32 f16, split-f16 3-product per tile
// (al*bh + ah*bl + ah*bh; the ll term ~2^-22 is dropped).
//   y in {0,1}: h[:, y*128 .. +127] = silu(x @ W1 + b1)
//   y == 2   : P[:, 0..79]          = x @ A'
// x staged fp32->LDS f16 hi/lo, double-buffered, layout [kq][row][8] so each
// 16-lane fragment read is a contiguous 256B chunk (conflict-free).
// Weight fragments load straight from packed global (L2-resident, 2.75 MB).
// 768 blocks = 3/CU exactly.
// ---------------------------------------------------------------------------
__global__ __launch_bounds__(256, 3) void xgemm_kernel(
    const float* __restrict__ x, const float* __restrict__ b1,
    const _Float16* __restrict__ Whi, const _Float16* __restrict__ Wlo,
    float* __restrict__ h, float* __restrict__ P) {
  __shared__ _Float16 lds[2][2][4][64][8];  // [buf][hi/lo][kq][row][8] = 16 KB
  const int t = threadIdx.x;
  const int tok0 = blockIdx.x * 64;
  const int y = blockIdx.y;
  const int lane = t & 63;
  const int w = t >> 6;          // wave 0..3
  const int sr = t >> 2;         // staging row 0..63
  const int sq = t & 3;          // staging k-quarter
  const int lq = lane >> 4;      // lane k-quarter
  const int lp = lane & 15;      // lane parallel index

  const float* xrow = x + (size_t)(tok0 + sr) * D_DIM + (sq << 3);

  // prologue: stage kg=0 into buf 0
  {
    float xv[8];
    *(float4*)&xv[0] = *(const float4*)(xrow);
    *(float4*)&xv[4] = *(const float4*)(xrow + 4);
    half8 hv, lv;
#pragma unroll
    for (int j = 0; j < 8; ++j) {
      const _Float16 hh = (_Float16)xv[j];
      hv[j] = hh;
      lv[j] = (_Float16)(xv[j] - (float)hh);
    }
    *(half8*)&lds[0][0][sq][sr][0] = hv;
    *(half8*)&lds[0][1][sq][sr][0] = lv;
  }

  const half8* WH = (const half8*)Whi;
  const half8* WL = (const half8*)Wlo;

  if (y < 2) {
    f32x4 acc[4][2];
#pragma unroll
    for (int i = 0; i < 4; ++i)
#pragma unroll
      for (int j = 0; j < 2; ++j) acc[i][j] = (f32x4)0.f;
    const int ctg0 = (y << 3) + (w << 1);  // wave owns 2 col-tiles
    int cur = 0;
    for (int kg = 0; kg < KG_N; ++kg) {
      __syncthreads();
      float xv[8];
      if (kg < KG_N - 1) {  // prefetch next x chunk early
        *(float4*)&xv[0] = *(const float4*)(xrow + (kg + 1) * 32);
        *(float4*)&xv[4] = *(const float4*)(xrow + (kg + 1) * 32 + 4);
      }
      half8 bh[2], bl[2], ah[4], al[4];
#pragma unroll
      for (int ct = 0; ct < 2; ++ct) {
        const size_t wo = ((size_t)(ctg0 + ct) * 64 + kg) * 64 + lane;
        bh[ct] = WH[wo];
        bl[ct] = WL[wo];
      }
#pragma unroll
      for (int rt = 0; rt < 4; ++rt) {
        ah[rt] = *(const half8*)&lds[cur][0][lq][(rt << 4) + lp][0];
        al[rt] = *(const half8*)&lds[cur][1][lq][(rt << 4) + lp][0];
      }
#pragma unroll
      for (int rt = 0; rt < 4; ++rt)
#pragma unroll
        for (int ct = 0; ct < 2; ++ct) {
          acc[rt][ct] = __builtin_amdgcn_mfma_f32_16x16x32_f16(al[rt], bh[ct], acc[rt][ct], 0, 0, 0);
          acc[rt][ct] = __builtin_amdgcn_mfma_f32_16x16x32_f16(ah[rt], bl[ct], acc[rt][ct], 0, 0, 0);
          acc[rt][ct] = __builtin_amdgcn_mfma_f32_16x16x32_f16(ah[rt], bh[ct], acc[rt][ct], 0, 0, 0);
        }
      if (kg < KG_N - 1) {
        half8 hv, lv;
#pragma unroll
        for (int j = 0; j < 8; ++j) {
          const _Float16 hh = (_Float16)xv[j];
          hv[j] = hh;
          lv[j] = (_Float16)(xv[j] - (float)hh);
        }
        *(half8*)&lds[cur ^ 1][0][sq][sr][0] = hv;
        *(half8*)&lds[cur ^ 1][1][sq][sr][0] = lv;
      }
      cur ^= 1;
    }
    // epilogue: + b1, silu, store h
    const int colb = (y << 7) + (w << 5);
#pragma unroll
    for (int rt = 0; rt < 4; ++rt)
#pragma unroll
      for (int ct = 0; ct < 2; ++ct) {
        const int col = colb + (ct << 4) + lp;
        const float bb = b1[col];
#pragma unroll
        for (int rg = 0; rg < 4; ++rg) {
          const int row = tok0 + (rt << 4) + (lq << 2) + rg;
          float v = acc[rt][ct][rg] + bb;
          v = v / (1.f + expf(-v));
          h[(size_t)row * H_DIM + col] = v;
        }
      }
  } else {
    // P path: wave owns 16 rows x all 80 cols (5 col-tiles)
    f32x4 acc[5];
#pragma unroll
    for (int j = 0; j < 5; ++j) acc[j] = (f32x4)0.f;
    int cur = 0;
    for (int kg = 0; kg < KG_N; ++kg) {
      __syncthreads();
      float xv[8];
      if (kg < KG_N - 1) {
        *(float4*)&xv[0] = *(const float4*)(xrow + (kg + 1) * 32);
        *(float4*)&xv[4] = *(const float4*)(xrow + (kg + 1) * 32 + 4);
      }
      half8 bh[5], bl[5];
#pragma unroll
      for (int ct = 0; ct < 5; ++ct) {
        const size_t wo = ((size_t)(16 + ct) * 64 + kg) * 64 + lane;
        bh[ct] = WH[wo];
        bl[ct] = WL[wo];
      }
      const half8 ah = *(const half8*)&lds[cur][0][lq][(w << 4) + lp][0];
      const half8 al = *(const half8*)&lds[cur][1][lq][(w << 4) + lp][0];
#pragma unroll
      for (int ct = 0; ct < 5; ++ct) {
        acc[ct] = __builtin_amdgcn_mfma_f32_16x16x32_f16(al, bh[ct], acc[ct], 0, 0, 0);
        acc[ct] = __builtin_amdgcn_mfma_f32_16x16x32_f16(ah, bl[ct], acc[ct], 0, 0, 0);
        acc[ct] = __builtin_amdgcn_mfma_f32_16x16x32_f16(ah, bh[ct], acc[ct], 0, 0, 0);
      }
      if (kg < KG_N - 1) {
        half8 hv, lv;
#pragma unroll
        for (int j = 0; j < 8; ++j) {
          const _Float16 hh = (_Float16)xv[j];
          hv[j] = hh;
          lv[j] = (_Float16)(xv[j] - (float)hh);
        }
        *(half8*)&lds[cur ^ 1][0][sq][sr][0] = hv;
        *(half8*)&lds[cur ^ 1][1][sq][sr][0] = lv;
      }
      cur ^= 1;
    }
#pragma unroll
    for (int ct = 0; ct < 5; ++ct)
#pragma unroll
      for (int rg = 0; rg < 4; ++rg) {
        const int row = tok0 + (w << 4) + (lq << 2) + rg;
        P[(size_t)row * ER + (ct << 4) + lp] = acc[ct][rg];
      }
  }
}

// ---------------------------------------------------------------------------
// route: logits = h@W2 + b2, top-2, pair-normalized weights; scales P in
// place by (selected ? 2*w : 0).  4 lanes per token, 64 tokens/block.
// (unchanged from the verified fp32 kernel)
// ---------------------------------------------------------------------------
__global__ __launch_bounds__(256) void route_kernel(
    const float* __restrict__ h, const float* __restrict__ W2,
    const float* __restrict__ b2, float* __restrict__ P) {
  __shared__ float w2s[H_DIM * E_NUM];
  const int t = threadIdx.x;
  for (int i = t; i < H_DIM * E_NUM; i += 256) w2s[i] = W2[i];
  __syncthreads();

  const int tok = blockIdx.x * 64 + (t >> 2);
  const int part = t & 3;
  float p[5] = {0.f, 0.f, 0.f, 0.f, 0.f};
  const float* hr = h + (size_t)tok * H_DIM + part * 64;
#pragma unroll
  for (int i = 0; i < 16; ++i) {
    float hv[4];
    *(float4*)hv = *(const float4*)(hr + (i << 2));
#pragma unroll
    for (int u = 0; u < 4; ++u) {
      const int c = part * 64 + (i << 2) + u;
#pragma unroll
      for (int e = 0; e < 5; ++e) p[e] = fmaf(hv[u], w2s[c * 5 + e], p[e]);
    }
  }
#pragma unroll
  for (int e = 0; e < 5; ++e) {
    p[e] += __shfl_xor(p[e], 1, 64);
    p[e] += __shfl_xor(p[e], 2, 64);
    p[e] += b2[e];
  }
  // top-2 by logits; strict > matches jax.lax.top_k tie order.
  int e0 = 0;
#pragma unroll
  for (int e = 1; e < 5; ++e) if (p[e] > p[e0]) e0 = e;
  int e1 = (e0 == 0) ? 1 : 0;
#pragma unroll
  for (int e = 0; e < 5; ++e) if (e != e0 && p[e] > p[e1]) e1 = e;
  const float q = expf(p[e1] - p[e0]);   // <= 1, stable
  const float s0 = 2.f / (1.f + q);      // SCALING * w0_normalized
  const float s1 = q * s0;               // SCALING * w1_normalized

  float* pr = P + (size_t)tok * ER + part * 20;
#pragma unroll
  for (int g = 0; g < 5; ++g) {
    float pv[4];
    *(float4*)pv = *(const float4*)(pr + (g << 2));
#pragma unroll
    for (int u = 0; u < 4; ++u) {
      const int e = (part * 20 + (g << 2) + u) >> 4;
      const float s = (e == e0) ? s0 : ((e == e1) ? s1 : 0.f);
      pv[u] *= s;
    }
    *(float4*)(pr + (g << 2)) = *(float4*)pv;
  }
}

// ---------------------------------------------------------------------------
// combine: out = base + P[N,80] @ B[80,2048].  P pre-scaled by route_kernel.
// (unchanged this round — becomes the top dispatch; diagnose with its
// counters next round)
// ---------------------------------------------------------------------------
__global__ __launch_bounds__(256) void combine_kernel(
    const float* __restrict__ P, const float* __restrict__ Bm,
    const float* __restrict__ base, float* __restrict__ out) {
  const int t = threadIdx.x;
  const int wg = __builtin_amdgcn_readfirstlane(t >> 6);  // wave-uniform
  const int c4 = ((blockIdx.x & 7) << 8) + ((t & 63) << 2);
  const int tok0 = ((blockIdx.x >> 3) << 6) + (wg << 4);

  float4 acc[16];
#pragma unroll
  for (int i = 0; i < 16; ++i) acc[i] = make_float4(0.f, 0.f, 0.f, 0.f);

  for (int k0 = 0; k0 < ER; k0 += 4) {
    const float4 bv0 = *(const float4*)(Bm + (size_t)(k0 + 0) * D_DIM + c4);
    const float4 bv1 = *(const float4*)(Bm + (size_t)(k0 + 1) * D_DIM + c4);
    const float4 bv2 = *(const float4*)(Bm + (size_t)(k0 + 2) * D_DIM + c4);
    const float4 bv3 = *(const float4*)(Bm + (size_t)(k0 + 3) * D_DIM + c4);
#pragma unroll
    for (int i = 0; i < 16; ++i) {
      const float* pr = P + (size_t)(tok0 + i) * ER + k0;  // uniform -> s_load
      const float p0 = pr[0], p1 = pr[1], p2 = pr[2], p3 = pr[3];
      acc[i].x = fmaf(p0, bv0.x, fmaf(p1, bv1.x, fmaf(p2, bv2.x, fmaf(p3, bv3.x, acc[i].x))));
      acc[i].y = fmaf(p0, bv0.y, fmaf(p1, bv1.y, fmaf(p2, bv2.y, fmaf(p3, bv3.y, acc[i].y))));
      acc[i].z = fmaf(p0, bv0.z, fmaf(p1, bv1.z, fmaf(p2, bv2.z, fmaf(p3, bv3.z, acc[i].z))));
      acc[i].w = fmaf(p0, bv0.w, fmaf(p1, bv1.w, fmaf(p2, bv2.w, fmaf(p3, bv3.w, acc[i].w))));
    }
  }

#pragma unroll
  for (int i = 0; i < 16; ++i) {
    const size_t o = (size_t)(tok0 + i) * D_DIM + c4;
    const float4 b = *(const float4*)(base + o);
    float4 r;
    r.x = acc[i].x + b.x;
    r.y = acc[i].y + b.y;
    r.z = acc[i].z + b.z;
    r.w = acc[i].w + b.w;
    *(float4*)(out + o) = r;
  }
}

// ---------------------------------------------------------------------------
extern "C" void kernel_launch(void* const* d_in, const int* in_sizes, int n_in,
                              void* d_out, int out_size, void* d_ws,
                              size_t ws_size, hipStream_t stream) {
  const float* x  = (const float*)d_in[0];
  const float* bo = (const float*)d_in[1];
  const float* A  = (const float*)d_in[2];
  const float* Bm = (const float*)d_in[3];
  const float* W1 = (const float*)d_in[4];
  const float* b1 = (const float*)d_in[5];
  const float* W2 = (const float*)d_in[6];
  const float* b2 = (const float*)d_in[7];
  float* out = (float*)d_out;

  char* ws = (char*)d_ws;
  float* h = (float*)ws;                               // [N][256] f32 = 16 MiB
  float* P = (float*)(ws + 16777216);                  // [N][80]  f32 = 5.25 MiB
  _Float16* Whi = (_Float16*)(ws + 16777216 + 5242880);            // 1.31 MiB
  _Float16* Wlo = (_Float16*)(ws + 16777216 + 5242880 + 1376256);  // 1.31 MiB

  pack_w_kernel<<<336, 256, 0, stream>>>(W1, A, Whi, Wlo);
  xgemm_kernel<<<dim3(N_TOK / 64, 3), 256, 0, stream>>>(x, b1, Whi, Wlo, h, P);
  route_kernel<<<N_TOK / 64, 256, 0, stream>>>(h, W2, b2, P);
  combine_kernel<<<(N_TOK / 64) * (D_DIM / 256), 256, 0, stream>>>(P, Bm, bo, out);
}